// Round 12
// baseline (5796.310 us; speedup 1.0000x reference)
//
#include <hip/hip_runtime.h>

// HybridQLSTM: B=64, S=2048, D=4 (2x2 conv), H=256, NCLS=2.
// R10 (3rd resubmit; rounds 9-11 were infra failures, kernel never ran):
// move the recurrent GEMV h@W_hh^T onto the MATRIX pipe.
// Evidence chain: R8 (fewer LDS ops: null) + R9 (pk_fma vs dot2: null) =>
// the VALU packed-f16 MAC rate (~4.5 cyc/instr, ~100 MACs/cyc/CU) is the
// binding roofline of the vector design. MFMA peak is ~38x that; even at
// M=1-in-16 tile waste it wins ~4x on paper.
// Design: 64 blocks x 256 threads (1 wave/SIMD -> 512-VGPR cap).
// Per wave: 16 N-tiles of 16 gates (units [64w..64w+64) x 4 gate types).
//   - B-frags tiles 0..11 register-resident (384 VGPR)
//   - B-frags tiles 12..15 in LDS (32KB/wave), conflict-free 16B/lane reads
//   - A = h broadcast (replicated across all 16 rows -> D rows identical;
//     every lane holds the result for col=l&15, lane groups are 4 copies)
//   - k-outer loop: 8 k-frags x 16 tiles = 128 MFMA/wave/step, 16 indep chains
//   - tail: input-proj + bias + LSTM cell on all lanes (redundant x4),
//     l<16 writes h to LDS (dbuf) + global hbuf.
// Fragment layouts (cdna4 §10 / m89-verified, dtype-independent):
//   A: lane l -> A[l&15][(l>>4)*8+j]   B: lane l -> B[(l>>4)*8+j][l&15]
//   D: col=lane&15, row=(lane>>4)*4+reg.
// prep packs W_hh into fragment order (Bpack) and W_ih+bias per (wave,col).

#define BB 64
#define SS 2048
#define HH 256

typedef _Float16 f16;
typedef _Float16 h2 __attribute__((ext_vector_type(2)));
typedef _Float16 v8h __attribute__((ext_vector_type(8)));
typedef float f32x4 __attribute__((ext_vector_type(4)));

union V8H { v8h v; h2 p[4]; };

__device__ __forceinline__ float fdot2f(h2 a, h2 b, float c){
#if __has_builtin(__builtin_amdgcn_fdot2)
  return __builtin_amdgcn_fdot2(a, b, c, false);
#else
  return c + (float)a.x*(float)b.x + (float)a.y*(float)b.y;
#endif
}

__device__ __forceinline__ float rcpf_(float x){
#if __has_builtin(__builtin_amdgcn_rcpf)
  return __builtin_amdgcn_rcpf(x);
#else
  return 1.f/x;
#endif
}
__device__ __forceinline__ float sigmf_(float x){ return rcpf_(1.f + __expf(-x)); }
__device__ __forceinline__ float tanhf_(float x){
  x = fminf(fmaxf(x, -15.f), 15.f);
  float e = __expf(2.f*x);
  return (e - 1.f)*rcpf_(e + 1.f);
}
__device__ __forceinline__ h2 mkh2(float a, float b){ h2 r; r.x=(f16)a; r.y=(f16)b; return r; }

// Raw barrier: orders LDS only (lgkmcnt); vmem stays outstanding across steps.
__device__ __forceinline__ void lds_barrier(){
  asm volatile("s_waitcnt lgkmcnt(0)\n\ts_barrier" ::: "memory");
}

// ----------------------------------------------------------------------------
// prep: linear job space.
// seg0 feat (131072), seg1 Bpack (32768), seg2 wihb (64), seg3 w1t (32768),
// seg4 w2t (32768), seg5 w3p (256). total 229696 -> 898 blocks x 256.
// Bpack[w][t][k][l] (16B each): 8 f16 = W_hh[n][kk..kk+7],
//   n = (t>>2)*256 + w*64 + (t&3)*16 + (l&15),  kk = k*32 + (l>>4)*8.
// wihb entry (w,c): 64 f16 {t=0..15: W_ih[n][0..3]} + 16 f32 bias {b_ih+b_hh}.
// ----------------------------------------------------------------------------
__global__ void prep_kernel(
    const float* __restrict__ x, const float* __restrict__ conv_w, const float* __restrict__ conv_b,
    const float* __restrict__ w_ih, const float* __restrict__ w_hh,
    const float* __restrict__ b_ih, const float* __restrict__ b_hh,
    const float* __restrict__ w1, const float* __restrict__ w2, const float* __restrict__ w3,
    f16* __restrict__ feat2, f16* __restrict__ Bpack, f16* __restrict__ wihb,
    f16* __restrict__ w1t, f16* __restrict__ w2t, f16* __restrict__ w3p)
{
  int id = blockIdx.x*256 + threadIdx.x;
  if (id < BB*SS){
    float4 xv = *(const float4*)(x + (size_t)id*4);
    float f0 = sigmf_(xv.x*conv_w[0] + conv_b[0]);
    float f1 = sigmf_(xv.y*conv_w[1] + conv_b[1]);
    float f2 = sigmf_(xv.z*conv_w[2] + conv_b[2]);
    float f3 = sigmf_(xv.w*conv_w[3] + conv_b[3]);
    h2* o = (h2*)feat2 + (size_t)id*2;
    o[0] = mkh2(f0,f1); o[1] = mkh2(f2,f3);
    return;
  }
  id -= BB*SS;
  if (id < 32768){
    int l = id & 63, k = (id>>6)&7, t = (id>>9)&15, w = (id>>13)&3;
    int n  = (t>>2)*256 + w*64 + (t&3)*16 + (l&15);
    int kk = k*32 + (l>>4)*8;
    const float* src = w_hh + (size_t)n*256 + kk;
    v8h o;
    #pragma unroll
    for (int j=0;j<8;j++) o[j] = (f16)src[j];
    *((v8h*)Bpack + id) = o;
    return;
  }
  id -= 32768;
  if (id < 64){
    int w = id >> 4, c = id & 15;
    f16* e = wihb + (size_t)id*96;       // 192 B per entry
    float* bf = (float*)(e + 64);        // bias block at +128 B
    #pragma unroll
    for (int t=0;t<16;t++){
      int n = (t>>2)*256 + w*64 + (t&3)*16 + c;
      e[t*4+0] = (f16)w_ih[n*4+0];
      e[t*4+1] = (f16)w_ih[n*4+1];
      e[t*4+2] = (f16)w_ih[n*4+2];
      e[t*4+3] = (f16)w_ih[n*4+3];
      bf[t] = b_ih[n] + b_hh[n];
    }
    return;
  }
  id -= 64;
  if (id < 32768){ // w1t[kp*256+n] = half2(w1[n][2kp], w1[n][2kp+1])
    int kp = id >> 8, n = id & 255;
    w1t[(size_t)id*2+0] = (f16)w1[(size_t)n*256 + 2*kp];
    w1t[(size_t)id*2+1] = (f16)w1[(size_t)n*256 + 2*kp+1];
    return;
  }
  id -= 32768;
  if (id < 32768){
    int kp = id >> 8, n = id & 255;
    w2t[(size_t)id*2+0] = (f16)w2[(size_t)n*256 + 2*kp];
    w2t[(size_t)id*2+1] = (f16)w2[(size_t)n*256 + 2*kp+1];
    return;
  }
  id -= 32768;
  if (id < 256){
    int kp = id >> 1, cls = id & 1;
    w3p[(size_t)id*2+0] = (f16)w3[(size_t)cls*256 + 2*kp];
    w3p[(size_t)id*2+1] = (f16)w3[(size_t)cls*256 + 2*kp+1];
  }
}

// ----------------------------------------------------------------------------
// LSTM via MFMA. 64 blocks x 256 threads (4 waves, 1/SIMD, 512-VGPR cap).
// LDS map (dynamic, 144384 B):
//   [0      .. 131072)  blds: 4 waves x 4 tiles x 8 k x 64 lanes x 16B
//   [131072 .. 132096)  h double buffer: 2 x 256 f16
//   [132096 .. 144384)  wihb copy: 64 entries x 192 B
// ----------------------------------------------------------------------------
#define LDS_H    131072
#define LDS_WIHB 132096
#define GLDS_BYTES 144384

__global__ __launch_bounds__(256, 1) void lstm_kernel(
    const f16* __restrict__ Bpack, const f16* __restrict__ feat2,
    const f16* __restrict__ wihb, f16* __restrict__ hbuf)
{
  extern __shared__ __align__(16) char glds[];
  const int b = blockIdx.x, tid = threadIdx.x;
  const int w = tid >> 6, l = tid & 63;
  const int grp = l >> 4, c = l & 15;

  // --- stage B fragments: tiles 0..11 -> registers (384 VGPR) ---
  const v8h* bp = (const v8h*)Bpack + (size_t)w*16*8*64;   // + (t*8+k)*64 + l
  v8h breg[12][8];
  #pragma unroll
  for (int t=0;t<12;t++)
    #pragma unroll
    for (int k=0;k<8;k++)
      breg[t][k] = bp[(t*8+k)*64 + l];

  // --- stage B tiles 12..15 -> LDS (32 KB per wave) ---
  {
    f16* bl = (f16*)glds + (size_t)w*16384;   // f16 units
    #pragma unroll
    for (int t2=0;t2<4;t2++)
      #pragma unroll
      for (int k=0;k<8;k++){
        v8h v = bp[((12+t2)*8+k)*64 + l];
        *(v8h*)(bl + (t2*8+k)*512 + l*8) = v;
      }
  }
  // --- wihb -> LDS (12288 B) ---
  {
    const int* src = (const int*)wihb;
    int* dst = (int*)(glds + LDS_WIHB);
    for (int i = tid; i < 3072; i += 256) dst[i] = src[i];
  }
  // --- h init (both buffers zero) ---
  f16* hb = (f16*)(glds + LDS_H);
  if (tid < 256){ hb[tid] = (f16)0.f; hb[256+tid] = (f16)0.f; }
  __syncthreads();

  const h2* fp = (const h2*)feat2 + (size_t)b*SS*2;
  f16* hrow = hbuf + (size_t)b*SS*HH;
  const f16* wl  = (const f16*)(glds + LDS_WIHB) + (size_t)(w*16 + c)*96;
  const float* blf = (const float*)(wl + 64);
  const f16* bldsr = (const f16*)glds + (size_t)w*16384 + l*8;
  float cst[4] = {0.f,0.f,0.f,0.f};
  int buf = 0;
  const f32x4 Z4 = {0.f,0.f,0.f,0.f};

  for (int s=0; s<SS; ++s){
    h2 f0 = fp[0], f1 = fp[1]; fp += 2;          // global; hides under MFMAs
    const f16* hq = hb + buf*256 + grp*8;        // A source: h broadcast
    f32x4 acc[16];
    #pragma unroll
    for (int k=0;k<8;k++){
      v8h a = *(const v8h*)(hq + k*32);
      #pragma unroll
      for (int t=0;t<12;t++){
        f32x4 cin = (k==0) ? Z4 : acc[t];
        acc[t] = __builtin_amdgcn_mfma_f32_16x16x32_f16(a, breg[t][k], cin, 0,0,0);
      }
      #pragma unroll
      for (int t2=0;t2<4;t2++){
        v8h bv = *(const v8h*)(bldsr + (t2*8+k)*512);
        f32x4 cin = (k==0) ? Z4 : acc[12+t2];
        acc[12+t2] = __builtin_amdgcn_mfma_f32_16x16x32_f16(a, bv, cin, 0,0,0);
      }
    }
    // --- D rows are identical (A rows identical): every lane holds the
    // result for col = l&15 in reg 0 of its row group; use acc[t][0].
    float pre[16];
    #pragma unroll
    for (int t=0;t<16;t++) pre[t] = acc[t][0];
    // input projection + bias (W_ih, bias from LDS; step-invariant reads)
    V8H wv[8];
    #pragma unroll
    for (int i=0;i<8;i++) wv[i].v = *(const v8h*)(wl + i*8);
    f32x4 bq[4];
    #pragma unroll
    for (int q=0;q<4;q++) bq[q] = *(const f32x4*)(blf + q*4);
    #pragma unroll
    for (int t=0;t<16;t++){
      h2 wa = wv[t>>1].p[(t&1)*2];
      h2 wb = wv[t>>1].p[(t&1)*2+1];
      pre[t] = fdot2f(wb, f1, fdot2f(wa, f0, pre[t] + bq[t>>2][t&3]));
    }
    // --- LSTM cell (t = g*4 + a: i:a, f:4+a, g:8+a, o:12+a) ---
    #pragma unroll
    for (int a2=0;a2<4;a2++){
      float iv = sigmf_(pre[a2]);
      float fv = sigmf_(pre[4+a2]);
      float gv = tanhf_(pre[8+a2]);
      float ov = sigmf_(pre[12+a2]);
      cst[a2] = fv*cst[a2] + iv*gv;
      float hn = ov*tanhf_(cst[a2]);
      if (l < 16){
        int u = w*64 + a2*16 + c;
        f16 hv = (f16)hn;
        hb[(buf^1)*256 + u] = hv;    // LDS h (next step's A)
        hrow[u] = hv;                // global, fire-and-forget
      }
    }
    hrow += HH;
    lds_barrier();                   // lgkm-only; vmem floats across steps
    buf ^= 1;
  }
}

// ----------------------------------------------------------------------------
// classifier: 16 rows per 256-thread block; 4x4 register tile per thread.
// Rows padded to 20 h2 (80 B): v8h reads stay 16B-aligned, dst writes 16-way
// instead of 64-way conflicts.
// ----------------------------------------------------------------------------
__device__ __forceinline__ void fc_layer(const h2 (*src)[20], h2 (*dst)[20],
                                         const f16* __restrict__ wt,
                                         const float* __restrict__ bias, int t)
{
  const int rg = t >> 6;           // row group 0..3
  const int c0 = (t & 63) * 4;     // 4 output cols
  float acc[4][4];
  #pragma unroll
  for (int r=0;r<4;r++){ acc[r][0]=0.f; acc[r][1]=0.f; acc[r][2]=0.f; acc[r][3]=0.f; }
  #pragma unroll 4
  for (int kp=0; kp<128; kp++){
    V8H wv; wv.v = *(const v8h*)(wt + ((size_t)kp*256 + c0)*2);
    V8H rv; rv.v = *(const v8h*)(&src[kp][rg*4]);
    #pragma unroll
    for (int r=0;r<4;r++)
      #pragma unroll
      for (int cc=0;cc<4;cc++)
        acc[r][cc] = fdot2f(rv.p[r], wv.p[cc], acc[r][cc]);
  }
  const float4 bv = *(const float4*)(bias + c0);
  #pragma unroll
  for (int r=0;r<4;r++){
    float o0 = fmaxf(acc[r][0]+bv.x, 0.f);
    float o1 = fmaxf(acc[r][1]+bv.y, 0.f);
    float o2 = fmaxf(acc[r][2]+bv.z, 0.f);
    float o3 = fmaxf(acc[r][3]+bv.w, 0.f);
    dst[(c0>>1)  ][rg*4+r] = mkh2(o0,o1);
    dst[(c0>>1)+1][rg*4+r] = mkh2(o2,o3);
  }
}

__global__ __launch_bounds__(256) void cls_kernel(
    const f16* __restrict__ hbuf, const f16* __restrict__ w1t, const f16* __restrict__ w2t,
    const f16* __restrict__ w3p, const float* __restrict__ b1, const float* __restrict__ b2,
    const float* __restrict__ b3, float* __restrict__ out)
{
  __shared__ __align__(16) h2 rlA[128][20];
  __shared__ __align__(16) h2 rlB[128][20];
  const int t = threadIdx.x;
  const size_t R = (size_t)blockIdx.x * 16;
  {
    int r = t >> 4, seg = t & 15;
    const v8h* src = (const v8h*)(hbuf + (R + r)*HH + seg*16);
    V8H aH; aH.v = src[0];
    V8H bH; bH.v = src[1];
    int kp0 = seg*8;
    #pragma unroll
    for (int j=0;j<4;j++) rlA[kp0+j  ][r] = aH.p[j];
    #pragma unroll
    for (int j=0;j<4;j++) rlA[kp0+4+j][r] = bH.p[j];
  }
  __syncthreads();
  fc_layer(rlA, rlB, w1t, b1, t);
  __syncthreads();
  fc_layer(rlB, rlA, w2t, b2, t);
  __syncthreads();
  if (t < 32){
    int r = t >> 1, cls = t & 1;
    float acc = b3[cls];
    const h2* w3h = (const h2*)w3p;
    #pragma unroll 8
    for (int kp=0; kp<128; kp++)
      acc = fdot2f(rlA[kp][r], w3h[kp*2 + cls], acc);
    out[(R + r)*2 + cls] = acc;
  }
}

// ----------------------------------------------------------------------------
extern "C" void kernel_launch(void* const* d_in, const int* in_sizes, int n_in,
                              void* d_out, int out_size, void* d_ws, size_t ws_size,
                              hipStream_t stream) {
  const float* x      = (const float*)d_in[0];
  const float* conv_w = (const float*)d_in[1];
  const float* conv_b = (const float*)d_in[2];
  const float* w_ih   = (const float*)d_in[3];
  const float* w_hh   = (const float*)d_in[4];
  const float* b_ih   = (const float*)d_in[5];
  const float* b_hh   = (const float*)d_in[6];
  const float* w1     = (const float*)d_in[7];
  const float* b1     = (const float*)d_in[8];
  const float* w2     = (const float*)d_in[9];
  const float* b2     = (const float*)d_in[10];
  const float* w3     = (const float*)d_in[11];
  const float* b3     = (const float*)d_in[12];

  char* ws = (char*)d_ws;
  f16*   feat2   = (f16*)  (ws + 0x000000);  // 1 MB
  f16*   Bpack   = (f16*)  (ws + 0x100000);  // 512 KB (W_hh fragment order)
  f16*   wihb    = (f16*)  (ws + 0x180000);  // 16 KB (W_ih + bias packed)
  f16*   w1t     = (f16*)  (ws + 0x190000);  // 128 KB
  f16*   w2t     = (f16*)  (ws + 0x1B0000);  // 128 KB
  f16*   w3p     = (f16*)  (ws + 0x1D0000);  // 1 KB
  f16*   hbuf    = (f16*)  (ws + 0x1E0000);  // 64 MB

  (void)hipFuncSetAttribute((const void*)lstm_kernel,
                            hipFuncAttributeMaxDynamicSharedMemorySize, GLDS_BYTES);

  prep_kernel<<<898, 256, 0, stream>>>(x, conv_w, conv_b, w_ih, w_hh, b_ih, b_hh,
                                       w1, w2, w3,
                                       feat2, Bpack, wihb, w1t, w2t, w3p);
  lstm_kernel<<<BB, 256, GLDS_BYTES, stream>>>(Bpack, feat2, wihb, hbuf);
  cls_kernel<<<(BB*SS)/16, 256, 0, stream>>>(hbuf, w1t, w2t, w3p, b1, b2, b3, (float*)d_out);
}